// Round 13
// baseline (281.566 us; speedup 1.0000x reference)
//
#include <hip/hip_runtime.h>
#include <hip/hip_bf16.h>

#define BATCH   32768
#define DM      1024
#define NE      16
#define THRESHF 0.3f
#define MARGIN  0.02f

// ws layout (bytes)
#define CTRL_OFF 131072
#define QBF_OFF  139264
#define PERM_OFF 172032
#define XBF_OFF  319488
#define WB_OFF   67428352ull
#define WS_NEED  (WB_OFF + (size_t)NE * DM * DM * 2)

typedef __attribute__((ext_vector_type(8))) short bf16x8;
typedef __attribute__((ext_vector_type(4))) float f32x4;

#define MFMA16(a, b, c) __builtin_amdgcn_mfma_f32_16x16x32_bf16(a, b, c, 0, 0, 0)

static __device__ __forceinline__ unsigned short f2bf(float f) {
    union { float f; unsigned u; } v; v.f = f;
    unsigned r = (v.u + 0x7FFFu + ((v.u >> 16) & 1u)) >> 16;  // RNE
    return (unsigned short)r;
}
static __device__ __forceinline__ float bf2f(unsigned short h) {
    union { unsigned u; float f; } v; v.u = ((unsigned)h) << 16;
    return v.f;
}

static __device__ __forceinline__ void gload_lds16(const void* g, void* s) {
    __builtin_amdgcn_global_load_lds(
        (const __attribute__((address_space(1))) void*)g,
        (__attribute__((address_space(3))) void*)s, 16, 0, 0);
}

// Local tile-base from final counts at granularity G (param: 256 full / 128 small).
static __device__ __forceinline__ int tile_base(const unsigned* ctrl, int* tb, int G) {
    int acc = 0;
#pragma unroll
    for (int e = 0; e < NE; ++e) {
        tb[e] = acc;
        acc += (int)((ctrl[e * 16] + (unsigned)(G - 1)) / (unsigned)G);
    }
    tb[NE] = acc;
    return acc;
}

// Zero ctrl, build ternary pack table + bf16 ternary Q, prefill perm with 0.
__global__ void k_init(const float* __restrict__ sig, unsigned* __restrict__ ctrl,
                       int* __restrict__ perm, unsigned short* __restrict__ Qbf) {
    const int t = blockIdx.x * 256 + threadIdx.x;  // 0..16383
    if (t < 544) ctrl[t] = 0;
    if (t < 1024) {
        unsigned pm = 0, mm = 0;
#pragma unroll
        for (int e = 0; e < NE; ++e) {
            float s = sig[e * DM + t];
            pm |= (s > THRESHF ? 1u : 0u) << e;
            mm |= (s < -THRESHF ? 1u : 0u) << e;
        }
        ctrl[1024 + t] = pm | (mm << 16);
    }
    if (t < 9216) ((int4*)perm)[t] = make_int4(0, 0, 0, 0);
    {
        float s = sig[t];
        Qbf[t] = s > THRESHF ? (unsigned short)0x3F80u
                             : (s < -THRESHF ? (unsigned short)0xBF80u : (unsigned short)0u);
    }
}

// Split-K MFMA router (proven R11): one block per 16-row group; 4 waves each
// own a 256-dim K-slice; LDS combine; wave 0 argmax + exact f64 fallback.
__global__ __launch_bounds__(256) void k_router(const float* __restrict__ x,
                                                const unsigned short* __restrict__ Qbf,
                                                unsigned* __restrict__ ctrl,
                                                int* __restrict__ idx,
                                                float* __restrict__ outIdx,
                                                unsigned short* __restrict__ Xbf,
                                                int writeXbf) {
    __shared__ float S[4][64][4];
    const int t = threadIdx.x, w = t >> 6, l = t & 63;
    const int lc = l & 15, lr = l >> 4;
    const int row0 = blockIdx.x * 16;
    const unsigned* packT = ctrl + 1024;

    const float* ax = x + (size_t)(row0 + lc) * DM + lr * 8;
    const unsigned short* qx = Qbf + (size_t)lc * DM + lr * 8;
    unsigned short* xb = Xbf + (size_t)(row0 + lc) * DM + lr * 8;

    f32x4 acc = (f32x4){0.f, 0.f, 0.f, 0.f};

    for (int kt = w * 4; kt < w * 4 + 4; ++kt) {
#pragma unroll
        for (int h = 0; h < 2; ++h) {
            const int ko = kt * 64 + h * 32;
            float4 v0 = *(const float4*)(ax + ko);
            float4 v1 = *(const float4*)(ax + ko + 4);
            bf16x8 q = *(const bf16x8*)(qx + ko);

            float f[8] = {v0.x, v0.y, v0.z, v0.w, v1.x, v1.y, v1.z, v1.w};
            bf16x8 ah, al;
#pragma unroll
            for (int j = 0; j < 8; ++j) {
                unsigned short hi = f2bf(f[j]);
                float r = f[j] - bf2f(hi);
                ah[j] = (short)hi;
                al[j] = (short)f2bf(r);
            }
            if (writeXbf) *(bf16x8*)(xb + ko) = ah;
            acc = MFMA16(ah, q, acc);
            acc = MFMA16(al, q, acc);
        }
    }

    *(f32x4*)&S[w][l][0] = acc;
    __syncthreads();
    if (w != 0) return;

#pragma unroll
    for (int s = 1; s < 4; ++s) acc += *(const f32x4*)&S[s][l][0];

    float bv[4]; int bi[4]; float gap[4];
#pragma unroll
    for (int reg = 0; reg < 4; ++reg) {
        float v = acc[reg]; int i = lc; float s = -3.4e38f;
#pragma unroll
        for (int m = 1; m < 16; m <<= 1) {
            float ov = __shfl_xor(v, m, 64);
            int oi = __shfl_xor(i, m, 64);
            float os = __shfl_xor(s, m, 64);
            bool take = (ov > v) || (ov == v && oi < i);
            float loser = take ? v : ov;
            v = take ? ov : v;
            i = take ? oi : i;
            s = fmaxf(fmaxf(s, os), loser);
        }
        bv[reg] = v; bi[reg] = i; gap[reg] = v - s;
    }

    unsigned flagsw = 0;
#pragma unroll
    for (int reg = 0; reg < 4; ++reg)
        flagsw |= (gap[reg] < MARGIN ? 1u : 0u) << reg;

    if (__any(lc == 0 && flagsw != 0)) {   // rare exact path
#pragma unroll
        for (int reg = 0; reg < 4; ++reg) {
            for (int g = 0; g < 4; ++g) {
                const unsigned fw = __shfl(flagsw, g * 16, 64);
                if ((fw >> reg) & 1u) {
                    const int row = row0 + g * 4 + reg;
                    const float* xr = x + (size_t)row * DM;
                    float xv[16]; unsigned mk[16];
#pragma unroll
                    for (int k2 = 0; k2 < 16; ++k2) {
                        xv[k2] = xr[k2 * 64 + l];
                        mk[k2] = packT[k2 * 64 + l];
                    }
                    double best = 0.0; int bbi = 0;
                    for (int e = 0; e < 16; ++e) {
                        double a = 0.0;
#pragma unroll
                        for (int k2 = 0; k2 < 16; ++k2) {
                            const int pb = (int)((mk[k2] >> e) & 1u);
                            const int mb = (int)((mk[k2] >> (16 + e)) & 1u);
                            a += pb ? (double)xv[k2] : (mb ? -(double)xv[k2] : 0.0);
                        }
#pragma unroll
                        for (int m = 1; m < 64; m <<= 1) a += __shfl_xor(a, m, 64);
                        if (e == 0 || a > best) { best = a; bbi = e; }
                    }
                    if (lr == g && lc == 0) bi[reg] = bbi;
                }
            }
        }
    }

    if (lc == 0) {
#pragma unroll
        for (int reg = 0; reg < 4; ++reg) {
            const int row = row0 + lr * 4 + reg;
            idx[row] = bi[reg];
            outIdx[row] = (float)bi[reg];
            atomicAdd(&ctrl[bi[reg] * 16], 1u);
        }
    }
}

// Fused: blocks 0..127 build perm (granularity G); blocks 128.. convert W.
__global__ __launch_bounds__(256) void k_permconv(const int* __restrict__ idx,
                                                  unsigned* __restrict__ ctrl,
                                                  int* __restrict__ perm,
                                                  const float* __restrict__ W,
                                                  unsigned short* __restrict__ Wb,
                                                  int G) {
    if (blockIdx.x >= 128) {
        const size_t g = ((size_t)(blockIdx.x - 128) * 256 + threadIdx.x) * 8;
        float4 a = *(const float4*)&W[g];
        float4 b = *(const float4*)&W[g + 4];
        *(ushort4*)&Wb[g]     = make_ushort4(f2bf(a.x), f2bf(a.y), f2bf(a.z), f2bf(a.w));
        *(ushort4*)&Wb[g + 4] = make_ushort4(f2bf(b.x), f2bf(b.y), f2bf(b.z), f2bf(b.w));
        return;
    }
    __shared__ unsigned hcnt[16];
    __shared__ unsigned hbase[16];
    const int t = threadIdx.x;
    const int row = blockIdx.x * 256 + t;
    int tb[NE + 1];
    tile_base(ctrl, tb, G);
    if (t < 16) hcnt[t] = 0;
    __syncthreads();
    const int e = idx[row];
    const unsigned lrank = atomicAdd(&hcnt[e], 1u);
    __syncthreads();
    if (t < 16) hbase[t] = atomicAdd(&ctrl[256 + t * 16], hcnt[t]);
    __syncthreads();
    perm[tb[e] * G + hbase[e] + lrank] = row;
}

// Grouped bf16 GEMM (R13): 256x256 tile, BK=32, 8 waves (2m x 4n, 512 thr),
// per-wave 128x64 out (8x4 frags, 32 MFMA/iter). Staged bytes per FLOP =
// (BM+BN)/(BM*BN) = 1/128 — 2x better than 128², 1.33x better than 128x256;
// the R12 post-mortem showed the iteration period equals staged-byte delivery
// time, so tile AREA is the lever. Sync skeleton = R7's proven loop verbatim:
// 3 buffers (depth-2), 1 barrier/iter, counted vmcnt(4) (STAGE = 4 VMEM/thr:
// 2 A + 2 B). LDS 96 KB -> 1 block/CU, 8 waves (VGPR ~200 <= 256 keeps 8).
// Chunk-swizzle (both-sides, rule #21) unchanged — conflict-free (R6: 0).
__global__ __launch_bounds__(512) void k_gemm(
        const unsigned short* __restrict__ Xbf,
        const unsigned short* __restrict__ Wb,
        const float* __restrict__ bias,
        const int* __restrict__ perm,
        const unsigned* __restrict__ ctrl,
        float* __restrict__ out) {
    __shared__ unsigned short A_lds[3][256 * 32];
    __shared__ unsigned short B_lds[3][256 * 32];

    int tb[NE + 1];
    const int total = tile_base(ctrl, tb, 256);

    // flat 0..575: xcd = flat&7; per-XCD 18 bx x 4 ny (siblings share L2).
    int bx, ny;
    {
        const int flat = blockIdx.x;
        const int xcd = flat & 7, s2 = flat >> 3;   // s2 0..71
        bx = xcd * 18 + (s2 >> 2);
        ny = s2 & 3;
    }
    if (bx >= total) return;
    int e = 0;
    while (e < NE - 1 && tb[e + 1] <= bx) ++e;
    const int valid = (int)ctrl[e * 16] - (bx - tb[e]) * 256;  // 1..256
    const int n0 = ny * 256;

    const int t = threadIdx.x, w = t >> 6, l = t & 63;
    const int wr = w >> 2, wc = w & 3;              // 2m x 4n wave grid
    const int lc = l & 15, lr = l >> 4;
    const int hsw = ((t & 3) - ((t >> 3) & 3)) & 3; // staged data-chunk
    const int ssw = (lr + (lc >> 1)) & 3;           // read slot-chunk

    f32x4 acc[8][4];
#pragma unroll
    for (int m = 0; m < 8; ++m)
#pragma unroll
        for (int n = 0; n < 4; ++n) acc[m][n] = (f32x4){0.f, 0.f, 0.f, 0.f};

    const size_t aRowBase = (size_t)bx * 256;
    const unsigned short* Bg = Wb + ((size_t)e * DM + n0) * DM;

    // Per-lane sources: thread t stages A rows {t>>2, 128+(t>>2)} and
    // B rows {t>>2, 128+(t>>2)}, chunk hsw (row>>1 parity matches: +128 rows
    // keeps (row>>1)&3 shift consistent since 128>>1=64 ≡ 0 mod 4).
    const int r0 = t >> 2;
    const int prow0 = perm[aRowBase + r0];
    const int prow1 = perm[aRowBase + 128 + r0];
    const unsigned short* a0 = Xbf + (size_t)prow0 * DM + hsw * 8;
    const unsigned short* a1 = Xbf + (size_t)prow1 * DM + hsw * 8;
    const unsigned short* b0 = Bg + (size_t)r0 * DM + hsw * 8;
    const unsigned short* b1 = Bg + (size_t)(128 + r0) * DM + hsw * 8;

    auto STAGE = [&](int kt, int buf) {   // 4 VMEM ops/thread
        const int ko = kt * 32;
        gload_lds16(a0 + ko, &A_lds[buf][(size_t)(w * 64) * 8]);
        gload_lds16(a1 + ko, &A_lds[buf][(size_t)(512 + w * 64) * 8]);
        gload_lds16(b0 + ko, &B_lds[buf][(size_t)(w * 64) * 8]);
        gload_lds16(b1 + ko, &B_lds[buf][(size_t)(512 + w * 64) * 8]);
    };

    STAGE(0, 0);
    STAGE(1, 1);

    const int NT = DM / 32;  // 32
    int cur = 0;
    for (int kt = 0; kt < NT; ++kt) {
        if (kt + 1 < NT) asm volatile("s_waitcnt vmcnt(4)" ::: "memory");
        else             asm volatile("s_waitcnt vmcnt(0)" ::: "memory");
        __builtin_amdgcn_sched_barrier(0);
        __builtin_amdgcn_s_barrier();
        __builtin_amdgcn_sched_barrier(0);

        if (kt + 2 < NT) {
            const int nb = (cur + 2 >= 3) ? cur - 1 : cur + 2;
            STAGE(kt + 2, nb);
        }

        bf16x8 bf[4];
#pragma unroll
        for (int n = 0; n < 4; ++n)
            bf[n] = *(const bf16x8*)&B_lds[cur][(wc * 64 + n * 16 + lc) * 32 + ssw * 8];
#pragma unroll
        for (int m = 0; m < 8; ++m) {
            bf16x8 af = *(const bf16x8*)&A_lds[cur][(wr * 128 + m * 16 + lc) * 32 + ssw * 8];
#pragma unroll
            for (int n = 0; n < 4; ++n)
                acc[m][n] = MFMA16(af, bf[n], acc[m][n]);
        }

        cur = (cur + 1 >= 3) ? 0 : cur + 1;
    }

    float bvv[4];
#pragma unroll
    for (int n = 0; n < 4; ++n) bvv[n] = bias[e * DM + n0 + wc * 64 + n * 16 + lc];

#pragma unroll
    for (int m = 0; m < 8; ++m) {
#pragma unroll
        for (int reg = 0; reg < 4; ++reg) {
            const int rit = wr * 128 + m * 16 + lr * 4 + reg;  // row in tile
            if (rit < valid) {
                const int orow = perm[aRowBase + rit];
                float* op = out + (size_t)orow * DM;
                const unsigned short* xr = Xbf + (size_t)orow * DM;
#pragma unroll
                for (int n = 0; n < 4; ++n) {
                    const int col = n0 + wc * 64 + n * 16 + lc;
                    float v = acc[m][n][reg] + bvv[n];
                    v = v > 0.f ? v : 0.f;
                    op[col] = v + bf2f(xr[col]);
                }
            }
        }
    }
}

// Fallback (small ws): 128x128 2-phase reg-staged f32->bf16 (G=128).
__global__ __launch_bounds__(256) void k_gemm_small(
        const float* __restrict__ x, const float* __restrict__ W,
        const float* __restrict__ bias, const int* __restrict__ perm,
        const unsigned* __restrict__ ctrl, float* __restrict__ out) {
    __shared__ unsigned short A_lds[128 * 32];
    __shared__ unsigned short B_lds[128 * 32];
    int tb[NE + 1];
    const int total = tile_base(ctrl, tb, 128);
    int bx, ny;
    {
        const int flat = blockIdx.x;
        const int xcd = flat & 7, s2 = flat >> 3;
        bx = xcd * 34 + (s2 >> 3);
        ny = s2 & 7;
    }
    if (bx >= total) return;
    int e = 0;
    while (e < NE - 1 && tb[e + 1] <= bx) ++e;
    const int valid = (int)ctrl[e * 16] - (bx - tb[e]) * 128;
    const int n0 = ny * 128;
    const int t = threadIdx.x, w = t >> 6, l = t & 63;
    const int wr = w >> 1, wc = w & 1;
    const int lc = l & 15, lr = l >> 4;
    const int hsw = ((t & 3) - ((t >> 3) & 3)) & 3;
    const int ssw = (lr + (lc >> 1)) & 3;

    f32x4 acc[4][4];
#pragma unroll
    for (int m = 0; m < 4; ++m)
#pragma unroll
        for (int n = 0; n < 4; ++n) acc[m][n] = (f32x4){0.f, 0.f, 0.f, 0.f};
    const size_t aRowBase = (size_t)bx * 128;

    for (int kt = 0; kt < DM / 32; ++kt) {
        __syncthreads();
#pragma unroll
        for (int rd = 0; rd < 2; ++rd) {
            const int c = rd * 256 + t;
            const int r = c >> 2;
            const float* wp = W + ((size_t)e * DM + n0 + r) * DM + kt * 32 + hsw * 8;
            float4 q0 = *(const float4*)wp;
            float4 q1 = *(const float4*)(wp + 4);
            *(ushort4*)&B_lds[c * 8]     = make_ushort4(f2bf(q0.x), f2bf(q0.y), f2bf(q0.z), f2bf(q0.w));
            *(ushort4*)&B_lds[c * 8 + 4] = make_ushort4(f2bf(q1.x), f2bf(q1.y), f2bf(q1.z), f2bf(q1.w));
            ushort4 p0 = make_ushort4(0, 0, 0, 0), p1 = p0;
            if (r < valid) {
                const int orow = perm[aRowBase + r];
                const float* xp = x + (size_t)orow * DM + kt * 32 + hsw * 8;
                float4 u0 = *(const float4*)xp;
                float4 u1 = *(const float4*)(xp + 4);
                p0 = make_ushort4(f2bf(u0.x), f2bf(u0.y), f2bf(u0.z), f2bf(u0.w));
                p1 = make_ushort4(f2bf(u1.x), f2bf(u1.y), f2bf(u1.z), f2bf(u1.w));
            }
            *(ushort4*)&A_lds[c * 8]     = p0;
            *(ushort4*)&A_lds[c * 8 + 4] = p1;
        }
        __syncthreads();
        bf16x8 af[4], bf[4];
#pragma unroll
        for (int m = 0; m < 4; ++m)
            af[m] = *(const bf16x8*)&A_lds[(wr * 64 + m * 16 + lc) * 32 + ssw * 8];
#pragma unroll
        for (int n = 0; n < 4; ++n)
            bf[n] = *(const bf16x8*)&B_lds[(wc * 64 + n * 16 + lc) * 32 + ssw * 8];
#pragma unroll
        for (int m = 0; m < 4; ++m)
#pragma unroll
            for (int n = 0; n < 4; ++n)
                acc[m][n] = MFMA16(af[m], bf[n], acc[m][n]);
    }

    float bvv[4];
#pragma unroll
    for (int n = 0; n < 4; ++n) bvv[n] = bias[e * DM + n0 + wc * 64 + n * 16 + lc];
#pragma unroll
    for (int m = 0; m < 4; ++m)
#pragma unroll
        for (int reg = 0; reg < 4; ++reg) {
            const int rit = wr * 64 + m * 16 + lr * 4 + reg;
            if (rit < valid) {
                const int orow = perm[aRowBase + rit];
                const float* xr = x + (size_t)orow * DM;
                float* op = out + (size_t)orow * DM;
#pragma unroll
                for (int n = 0; n < 4; ++n) {
                    const int col = n0 + wc * 64 + n * 16 + lc;
                    float v = acc[m][n][reg] + bvv[n];
                    v = v > 0.f ? v : 0.f;
                    op[col] = v + xr[col];
                }
            }
        }
}

extern "C" void kernel_launch(void* const* d_in, const int* in_sizes, int n_in,
                              void* d_out, int out_size, void* d_ws, size_t ws_size,
                              hipStream_t stream) {
    const float* x    = (const float*)d_in[0];
    const float* sig  = (const float*)d_in[1];
    const float* W    = (const float*)d_in[2];
    const float* bias = (const float*)d_in[3];
    float* out = (float*)d_out;
    float* outIdx = out + (size_t)BATCH * DM;

    char* ws = (char*)d_ws;
    int* idx = (int*)ws;
    unsigned* ctrl = (unsigned*)(ws + CTRL_OFF);
    unsigned short* Qbf = (unsigned short*)(ws + QBF_OFF);
    int* perm = (int*)(ws + PERM_OFF);
    unsigned short* Xbf = (unsigned short*)(ws + XBF_OFF);
    unsigned short* Wb = (unsigned short*)(ws + WB_OFF);

    const bool full = ws_size >= WS_NEED;
    const int G = full ? 256 : 128;

    k_init<<<64, 256, 0, stream>>>(sig, ctrl, perm, Qbf);
    k_router<<<2048, 256, 0, stream>>>(x, Qbf, ctrl, idx, outIdx, Xbf, full ? 1 : 0);
    k_permconv<<<full ? 8320 : 128, 256, 0, stream>>>(idx, ctrl, perm, W, Wb, G);
    if (full) {
        k_gemm<<<576, 512, 0, stream>>>(Xbf, Wb, bias, perm, ctrl, out);
    } else {
        k_gemm_small<<<2176, 256, 0, stream>>>(x, W, bias, perm, ctrl, out);
    }
}

// Round 14
// 279.422 us; speedup vs baseline: 1.0077x; 1.0077x over previous
//
#include <hip/hip_runtime.h>
#include <hip/hip_bf16.h>

#define BATCH   32768
#define DM      1024
#define NE      16
#define THRESHF 0.3f
#define MARGIN  0.02f

// ws layout (bytes)
// idx   @ 0          : int32[32768]            = 131072
// ctrl  @ 131072     : u32[544] (counts/cursor strided; zeroed via memset)
// perm  @ 172032     : int32[36864]            (memset 0: pad slots -> row 0)
// Xbf   @ 319488     : bf16[32768*1024]
// Wb    @ 67428352   : bf16[16*1024*1024]
#define CTRL_OFF 131072
#define PERM_OFF 172032
#define XBF_OFF  319488
#define WB_OFF   67428352ull
#define WS_NEED  (WB_OFF + (size_t)NE * DM * DM * 2)

typedef __attribute__((ext_vector_type(8))) short bf16x8;
typedef __attribute__((ext_vector_type(4))) float f32x4;

#define MFMA16(a, b, c) __builtin_amdgcn_mfma_f32_16x16x32_bf16(a, b, c, 0, 0, 0)

static __device__ __forceinline__ unsigned short f2bf(float f) {
    union { float f; unsigned u; } v; v.f = f;
    unsigned r = (v.u + 0x7FFFu + ((v.u >> 16) & 1u)) >> 16;  // RNE
    return (unsigned short)r;
}
static __device__ __forceinline__ float bf2f(unsigned short h) {
    union { unsigned u; float f; } v; v.u = ((unsigned)h) << 16;
    return v.f;
}

static __device__ __forceinline__ void gload_lds16(const void* g, void* s) {
    __builtin_amdgcn_global_load_lds(
        (const __attribute__((address_space(1))) void*)g,
        (__attribute__((address_space(3))) void*)s, 16, 0, 0);
}

// Local tile-base from final counts at granularity G.
static __device__ __forceinline__ int tile_base(const unsigned* ctrl, int* tb, int G) {
    int acc = 0;
#pragma unroll
    for (int e = 0; e < NE; ++e) {
        tb[e] = acc;
        acc += (int)((ctrl[e * 16] + (unsigned)(G - 1)) / (unsigned)G);
    }
    tb[NE] = acc;
    return acc;
}

// ternary quantize a float to bf16 {-1,0,+1}
static __device__ __forceinline__ unsigned short qtern(float s) {
    return s > THRESHF ? (unsigned short)0x3F80u
                       : (s < -THRESHF ? (unsigned short)0xBF80u : (unsigned short)0u);
}

// Split-K MFMA router (R11 structure, R14: Q quantized inline from sig —
// no init kernel). One block per 16-row group; 4 waves each own a 256-dim
// K-slice; LDS combine; wave 0 argmax + exact f64 fallback (masks from sig).
__global__ __launch_bounds__(256) void k_router(const float* __restrict__ x,
                                                const float* __restrict__ sig,
                                                unsigned* __restrict__ ctrl,
                                                int* __restrict__ idx,
                                                float* __restrict__ outIdx,
                                                unsigned short* __restrict__ Xbf,
                                                int writeXbf) {
    __shared__ float S[4][64][4];
    const int t = threadIdx.x, w = t >> 6, l = t & 63;
    const int lc = l & 15, lr = l >> 4;
    const int row0 = blockIdx.x * 16;

    const float* ax = x + (size_t)(row0 + lc) * DM + lr * 8;
    const float* sx = sig + (size_t)lc * DM + lr * 8;
    unsigned short* xb = Xbf + (size_t)(row0 + lc) * DM + lr * 8;

    f32x4 acc = (f32x4){0.f, 0.f, 0.f, 0.f};

    for (int kt = w * 4; kt < w * 4 + 4; ++kt) {
#pragma unroll
        for (int h = 0; h < 2; ++h) {
            const int ko = kt * 64 + h * 32;
            float4 v0 = *(const float4*)(ax + ko);
            float4 v1 = *(const float4*)(ax + ko + 4);
            float4 s0 = *(const float4*)(sx + ko);
            float4 s1 = *(const float4*)(sx + ko + 4);

            float f[8] = {v0.x, v0.y, v0.z, v0.w, v1.x, v1.y, v1.z, v1.w};
            float sg[8] = {s0.x, s0.y, s0.z, s0.w, s1.x, s1.y, s1.z, s1.w};
            bf16x8 ah, al, q;
#pragma unroll
            for (int j = 0; j < 8; ++j) {
                unsigned short hi = f2bf(f[j]);
                float r = f[j] - bf2f(hi);
                ah[j] = (short)hi;
                al[j] = (short)f2bf(r);
                q[j] = (short)qtern(sg[j]);
            }
            if (writeXbf) *(bf16x8*)(xb + ko) = ah;
            acc = MFMA16(ah, q, acc);
            acc = MFMA16(al, q, acc);
        }
    }

    *(f32x4*)&S[w][l][0] = acc;
    __syncthreads();
    if (w != 0) return;

#pragma unroll
    for (int s = 1; s < 4; ++s) acc += *(const f32x4*)&S[s][l][0];

    float bv[4]; int bi[4]; float gap[4];
#pragma unroll
    for (int reg = 0; reg < 4; ++reg) {
        float v = acc[reg]; int i = lc; float s = -3.4e38f;
#pragma unroll
        for (int m = 1; m < 16; m <<= 1) {
            float ov = __shfl_xor(v, m, 64);
            int oi = __shfl_xor(i, m, 64);
            float os = __shfl_xor(s, m, 64);
            bool take = (ov > v) || (ov == v && oi < i);
            float loser = take ? v : ov;
            v = take ? ov : v;
            i = take ? oi : i;
            s = fmaxf(fmaxf(s, os), loser);
        }
        bv[reg] = v; bi[reg] = i; gap[reg] = v - s;
    }

    unsigned flagsw = 0;
#pragma unroll
    for (int reg = 0; reg < 4; ++reg)
        flagsw |= (gap[reg] < MARGIN ? 1u : 0u) << reg;

    if (__any(lc == 0 && flagsw != 0)) {   // rare exact path (masks from sig)
#pragma unroll
        for (int reg = 0; reg < 4; ++reg) {
            for (int g = 0; g < 4; ++g) {
                const unsigned fw = __shfl(flagsw, g * 16, 64);
                if ((fw >> reg) & 1u) {
                    const int row = row0 + g * 4 + reg;
                    const float* xr = x + (size_t)row * DM;
                    float xv[16];
#pragma unroll
                    for (int k2 = 0; k2 < 16; ++k2) xv[k2] = xr[k2 * 64 + l];
                    double best = 0.0; int bbi = 0;
                    for (int e = 0; e < 16; ++e) {
                        double a = 0.0;
#pragma unroll
                        for (int k2 = 0; k2 < 16; ++k2) {
                            const float s = sig[e * DM + k2 * 64 + l];
                            a += (s > THRESHF) ? (double)xv[k2]
                               : ((s < -THRESHF) ? -(double)xv[k2] : 0.0);
                        }
#pragma unroll
                        for (int m = 1; m < 64; m <<= 1) a += __shfl_xor(a, m, 64);
                        if (e == 0 || a > best) { best = a; bbi = e; }
                    }
                    if (lr == g && lc == 0) bi[reg] = bbi;
                }
            }
        }
    }

    if (lc == 0) {
#pragma unroll
        for (int reg = 0; reg < 4; ++reg) {
            const int row = row0 + lr * 4 + reg;
            idx[row] = bi[reg];
            outIdx[row] = (float)bi[reg];
            atomicAdd(&ctrl[bi[reg] * 16], 1u);
        }
    }
}

// Fused: blocks 0..127 build perm (granularity G); blocks 128.. convert W.
__global__ __launch_bounds__(256) void k_permconv(const int* __restrict__ idx,
                                                  unsigned* __restrict__ ctrl,
                                                  int* __restrict__ perm,
                                                  const float* __restrict__ W,
                                                  unsigned short* __restrict__ Wb,
                                                  int G) {
    if (blockIdx.x >= 128) {
        const size_t g = ((size_t)(blockIdx.x - 128) * 256 + threadIdx.x) * 8;
        float4 a = *(const float4*)&W[g];
        float4 b = *(const float4*)&W[g + 4];
        *(ushort4*)&Wb[g]     = make_ushort4(f2bf(a.x), f2bf(a.y), f2bf(a.z), f2bf(a.w));
        *(ushort4*)&Wb[g + 4] = make_ushort4(f2bf(b.x), f2bf(b.y), f2bf(b.z), f2bf(b.w));
        return;
    }
    __shared__ unsigned hcnt[16];
    __shared__ unsigned hbase[16];
    const int t = threadIdx.x;
    const int row = blockIdx.x * 256 + t;
    int tb[NE + 1];
    tile_base(ctrl, tb, G);
    if (t < 16) hcnt[t] = 0;
    __syncthreads();
    const int e = idx[row];
    const unsigned lrank = atomicAdd(&hcnt[e], 1u);
    __syncthreads();
    if (t < 16) hbase[t] = atomicAdd(&ctrl[256 + t * 16], hcnt[t]);
    __syncthreads();
    perm[tb[e] * G + hbase[e] + lrank] = row;
}

// Grouped bf16 GEMM: R7 pipeline verbatim (proven 142us; family floor per
// R7/R8/R9/R12/R13 response surface). 128x128 tile, BK=32, 4 waves (2x2),
// A and B triple-buffered (depth-2), counted vmcnt(4), 49KB LDS -> 3 blk/CU,
// chunk-swizzle (both-sides) — conflicts 0.
__global__ __launch_bounds__(256) void k_gemm(
        const unsigned short* __restrict__ Xbf,
        const unsigned short* __restrict__ Wb,
        const float* __restrict__ bias,
        const int* __restrict__ perm,
        const unsigned* __restrict__ ctrl,
        float* __restrict__ out) {
    __shared__ unsigned short A_lds[3][128 * 32];
    __shared__ unsigned short B_lds[3][128 * 32];

    int tb[NE + 1];
    const int total = tile_base(ctrl, tb, 128);

    // flat = 0..2175: xcd = flat&7; all 8 ny-siblings of one bx share an XCD.
    int bx, ny;
    {
        const int flat = blockIdx.x;
        const int xcd = flat & 7, s2 = flat >> 3;
        bx = xcd * 34 + (s2 >> 3);
        ny = s2 & 7;
    }
    if (bx >= total) return;
    int e = 0;
    while (e < NE - 1 && tb[e + 1] <= bx) ++e;
    const int valid = (int)ctrl[e * 16] - (bx - tb[e]) * 128;  // 1..128
    const int n0 = ny * 128;

    const int t = threadIdx.x, w = t >> 6, l = t & 63;
    const int wr = w >> 1, wc = w & 1;
    const int lc = l & 15, lr = l >> 4;
    const int hsw = ((t & 3) - ((t >> 3) & 3)) & 3;     // staged data-chunk
    const int ssw = (lr + (lc >> 1)) & 3;               // read slot-chunk

    f32x4 acc[4][4];
#pragma unroll
    for (int m = 0; m < 4; ++m)
#pragma unroll
        for (int n = 0; n < 4; ++n) acc[m][n] = (f32x4){0.f, 0.f, 0.f, 0.f};

    const size_t aRowBase = (size_t)bx * 128;
    const unsigned short* Bg = Wb + ((size_t)e * DM + n0) * DM;

    const int r0 = t >> 2;
    const int prow0 = perm[aRowBase + r0];
    const int prow1 = perm[aRowBase + 64 + r0];
    const unsigned short* a0 = Xbf + (size_t)prow0 * DM + hsw * 8;
    const unsigned short* a1 = Xbf + (size_t)prow1 * DM + hsw * 8;
    const unsigned short* b0 = Bg + (size_t)r0 * DM + hsw * 8;
    const unsigned short* b1 = Bg + (size_t)(64 + r0) * DM + hsw * 8;

    auto STAGE = [&](int kt, int buf) {   // 4 VMEM ops/thread
        const int ko = kt * 32;
        gload_lds16(a0 + ko, &A_lds[buf][(size_t)(w * 64) * 8]);
        gload_lds16(a1 + ko, &A_lds[buf][(size_t)(256 + w * 64) * 8]);
        gload_lds16(b0 + ko, &B_lds[buf][(size_t)(w * 64) * 8]);
        gload_lds16(b1 + ko, &B_lds[buf][(size_t)(256 + w * 64) * 8]);
    };

    STAGE(0, 0);
    STAGE(1, 1);

    const int NT = DM / 32;  // 32
    int cur = 0;
    for (int kt = 0; kt < NT; ++kt) {
        if (kt + 1 < NT) asm volatile("s_waitcnt vmcnt(4)" ::: "memory");
        else             asm volatile("s_waitcnt vmcnt(0)" ::: "memory");
        __builtin_amdgcn_sched_barrier(0);
        __builtin_amdgcn_s_barrier();
        __builtin_amdgcn_sched_barrier(0);

        if (kt + 2 < NT) {
            const int nb = (cur + 2 >= 3) ? cur - 1 : cur + 2;
            STAGE(kt + 2, nb);
        }

        bf16x8 af[4], bf[4];
#pragma unroll
        for (int m = 0; m < 4; ++m)
            af[m] = *(const bf16x8*)&A_lds[cur][(wr * 64 + m * 16 + lc) * 32 + ssw * 8];
#pragma unroll
        for (int n = 0; n < 4; ++n)
            bf[n] = *(const bf16x8*)&B_lds[cur][(wc * 64 + n * 16 + lc) * 32 + ssw * 8];
#pragma unroll
        for (int m = 0; m < 4; ++m)
#pragma unroll
            for (int n = 0; n < 4; ++n)
                acc[m][n] = MFMA16(af[m], bf[n], acc[m][n]);

        cur = (cur + 1 >= 3) ? 0 : cur + 1;
    }

    float bvv[4];
#pragma unroll
    for (int n = 0; n < 4; ++n) bvv[n] = bias[e * DM + n0 + wc * 64 + n * 16 + lc];

#pragma unroll
    for (int m = 0; m < 4; ++m) {
#pragma unroll
        for (int reg = 0; reg < 4; ++reg) {
            const int rit = wr * 64 + m * 16 + lr * 4 + reg;  // row in tile
            if (rit < valid) {
                const int orow = perm[aRowBase + rit];
                float* op = out + (size_t)orow * DM;
                const unsigned short* xr = Xbf + (size_t)orow * DM;
#pragma unroll
                for (int n = 0; n < 4; ++n) {
                    const int col = n0 + wc * 64 + n * 16 + lc;
                    float v = acc[m][n][reg] + bvv[n];
                    v = v > 0.f ? v : 0.f;
                    op[col] = v + bf2f(xr[col]);
                }
            }
        }
    }
}

// Fallback (small ws): 128x128 2-phase reg-staged f32->bf16 (G=128).
__global__ __launch_bounds__(256) void k_gemm_small(
        const float* __restrict__ x, const float* __restrict__ W,
        const float* __restrict__ bias, const int* __restrict__ perm,
        const unsigned* __restrict__ ctrl, float* __restrict__ out) {
    __shared__ unsigned short A_lds[128 * 32];
    __shared__ unsigned short B_lds[128 * 32];
    int tb[NE + 1];
    const int total = tile_base(ctrl, tb, 128);
    int bx, ny;
    {
        const int flat = blockIdx.x;
        const int xcd = flat & 7, s2 = flat >> 3;
        bx = xcd * 34 + (s2 >> 3);
        ny = s2 & 7;
    }
    if (bx >= total) return;
    int e = 0;
    while (e < NE - 1 && tb[e + 1] <= bx) ++e;
    const int valid = (int)ctrl[e * 16] - (bx - tb[e]) * 128;
    const int n0 = ny * 128;
    const int t = threadIdx.x, w = t >> 6, l = t & 63;
    const int wr = w >> 1, wc = w & 1;
    const int lc = l & 15, lr = l >> 4;
    const int hsw = ((t & 3) - ((t >> 3) & 3)) & 3;
    const int ssw = (lr + (lc >> 1)) & 3;

    f32x4 acc[4][4];
#pragma unroll
    for (int m = 0; m < 4; ++m)
#pragma unroll
        for (int n = 0; n < 4; ++n) acc[m][n] = (f32x4){0.f, 0.f, 0.f, 0.f};
    const size_t aRowBase = (size_t)bx * 128;

    for (int kt = 0; kt < DM / 32; ++kt) {
        __syncthreads();
#pragma unroll
        for (int rd = 0; rd < 2; ++rd) {
            const int c = rd * 256 + t;
            const int r = c >> 2;
            const float* wp = W + ((size_t)e * DM + n0 + r) * DM + kt * 32 + hsw * 8;
            float4 q0 = *(const float4*)wp;
            float4 q1 = *(const float4*)(wp + 4);
            *(ushort4*)&B_lds[c * 8]     = make_ushort4(f2bf(q0.x), f2bf(q0.y), f2bf(q0.z), f2bf(q0.w));
            *(ushort4*)&B_lds[c * 8 + 4] = make_ushort4(f2bf(q1.x), f2bf(q1.y), f2bf(q1.z), f2bf(q1.w));
            ushort4 p0 = make_ushort4(0, 0, 0, 0), p1 = p0;
            if (r < valid) {
                const int orow = perm[aRowBase + r];
                const float* xp = x + (size_t)orow * DM + kt * 32 + hsw * 8;
                float4 u0 = *(const float4*)xp;
                float4 u1 = *(const float4*)(xp + 4);
                p0 = make_ushort4(f2bf(u0.x), f2bf(u0.y), f2bf(u0.z), f2bf(u0.w));
                p1 = make_ushort4(f2bf(u1.x), f2bf(u1.y), f2bf(u1.z), f2bf(u1.w));
            }
            *(ushort4*)&A_lds[c * 8]     = p0;
            *(ushort4*)&A_lds[c * 8 + 4] = p1;
        }
        __syncthreads();
        bf16x8 af[4], bf[4];
#pragma unroll
        for (int m = 0; m < 4; ++m)
            af[m] = *(const bf16x8*)&A_lds[(wr * 64 + m * 16 + lc) * 32 + ssw * 8];
#pragma unroll
        for (int n = 0; n < 4; ++n)
            bf[n] = *(const bf16x8*)&B_lds[(wc * 64 + n * 16 + lc) * 32 + ssw * 8];
#pragma unroll
        for (int m = 0; m < 4; ++m)
#pragma unroll
            for (int n = 0; n < 4; ++n)
                acc[m][n] = MFMA16(af[m], bf[n], acc[m][n]);
    }

    float bvv[4];
#pragma unroll
    for (int n = 0; n < 4; ++n) bvv[n] = bias[e * DM + n0 + wc * 64 + n * 16 + lc];
#pragma unroll
    for (int m = 0; m < 4; ++m)
#pragma unroll
        for (int reg = 0; reg < 4; ++reg) {
            const int rit = wr * 64 + m * 16 + lr * 4 + reg;
            if (rit < valid) {
                const int orow = perm[aRowBase + rit];
                const float* xr = x + (size_t)orow * DM;
                float* op = out + (size_t)orow * DM;
#pragma unroll
                for (int n = 0; n < 4; ++n) {
                    const int col = n0 + wc * 64 + n * 16 + lc;
                    float v = acc[m][n][reg] + bvv[n];
                    v = v > 0.f ? v : 0.f;
                    op[col] = v + xr[col];
                }
            }
        }
}

extern "C" void kernel_launch(void* const* d_in, const int* in_sizes, int n_in,
                              void* d_out, int out_size, void* d_ws, size_t ws_size,
                              hipStream_t stream) {
    const float* x    = (const float*)d_in[0];
    const float* sig  = (const float*)d_in[1];
    const float* W    = (const float*)d_in[2];
    const float* bias = (const float*)d_in[3];
    float* out = (float*)d_out;
    float* outIdx = out + (size_t)BATCH * DM;

    char* ws = (char*)d_ws;
    int* idx = (int*)ws;
    unsigned* ctrl = (unsigned*)(ws + CTRL_OFF);
    int* perm = (int*)(ws + PERM_OFF);
    unsigned short* Xbf = (unsigned short*)(ws + XBF_OFF);
    unsigned short* Wb = (unsigned short*)(ws + WB_OFF);

    const bool full = ws_size >= WS_NEED;
    const int G = 128;

    // R14: init kernel replaced by two async memsets (graph-capture-safe).
    hipMemsetAsync(ctrl, 0, 544 * 4, stream);
    hipMemsetAsync(perm, 0, 36864 * 4, stream);
    k_router<<<2048, 256, 0, stream>>>(x, sig, ctrl, idx, outIdx, Xbf, full ? 1 : 0);
    k_permconv<<<full ? 8320 : 128, 256, 0, stream>>>(idx, ctrl, perm, W, Wb, G);
    if (full) {
        k_gemm<<<2176, 256, 0, stream>>>(Xbf, Wb, bias, perm, ctrl, out);
    } else {
        k_gemm_small<<<2176, 256, 0, stream>>>(x, W, bias, perm, ctrl, out);
    }
}

// Round 15
// 221.198 us; speedup vs baseline: 1.2729x; 1.2632x over previous
//
#include <hip/hip_runtime.h>
#include <hip/hip_bf16.h>

#define BATCH   32768
#define DM      1024
#define NE      16
#define THRESHF 0.3f
#define MARGIN  0.02f

// ws layout (bytes)
// idx   @ 0          : int32[32768]            = 131072
// ctrl  @ 131072     : u32[2048] (8192 B)
//    [e*16]        counts (one 64B line per expert)
//    [256 + e*16]  cursor (strided)
//    [1024..2047]  packT u32[1024] (pm | mm<<16 per dim)
// Qbf   @ 139264     : bf16[16*1024] ternary   = 32768
// perm  @ 172032     : int32[36864]            = 147456 (prefilled 0)
// Xbf   @ 319488     : bf16[32768*1024]        = 67108864
// Wb    @ 67428352   : bf16[16*1024*1024]      = 33554432  (ends ~96.3 MB)
#define CTRL_OFF 131072
#define QBF_OFF  139264
#define PERM_OFF 172032
#define XBF_OFF  319488
#define WB_OFF   67428352ull
#define WS_NEED  (WB_OFF + (size_t)NE * DM * DM * 2)

typedef __attribute__((ext_vector_type(8))) short bf16x8;
typedef __attribute__((ext_vector_type(4))) float f32x4;

#define MFMA16(a, b, c) __builtin_amdgcn_mfma_f32_16x16x32_bf16(a, b, c, 0, 0, 0)

static __device__ __forceinline__ unsigned short f2bf(float f) {
    union { float f; unsigned u; } v; v.f = f;
    unsigned r = (v.u + 0x7FFFu + ((v.u >> 16) & 1u)) >> 16;  // RNE
    return (unsigned short)r;
}
static __device__ __forceinline__ float bf2f(unsigned short h) {
    union { unsigned u; float f; } v; v.u = ((unsigned)h) << 16;
    return v.f;
}

static __device__ __forceinline__ void gload_lds16(const void* g, void* s) {
    __builtin_amdgcn_global_load_lds(
        (const __attribute__((address_space(1))) void*)g,
        (__attribute__((address_space(3))) void*)s, 16, 0, 0);
}

// Local tile-base from final counts (no k_scan dispatch): 16 adds.
static __device__ __forceinline__ int tile_base(const unsigned* ctrl, int* tb) {
    int acc = 0;
#pragma unroll
    for (int e = 0; e < NE; ++e) {
        tb[e] = acc;
        acc += (int)((ctrl[e * 16] + 127u) >> 7);
    }
    tb[NE] = acc;
    return acc;
}

// Zero ctrl, build ternary pack table + bf16 ternary Q, prefill perm with 0.
__global__ void k_init(const float* __restrict__ sig, unsigned* __restrict__ ctrl,
                       int* __restrict__ perm, unsigned short* __restrict__ Qbf) {
    const int t = blockIdx.x * 256 + threadIdx.x;  // 0..16383
    if (t < 544) ctrl[t] = 0;
    if (t < 1024) {
        unsigned pm = 0, mm = 0;
#pragma unroll
        for (int e = 0; e < NE; ++e) {
            float s = sig[e * DM + t];
            pm |= (s > THRESHF ? 1u : 0u) << e;
            mm |= (s < -THRESHF ? 1u : 0u) << e;
        }
        ctrl[1024 + t] = pm | (mm << 16);
    }
    if (t < 9216) ((int4*)perm)[t] = make_int4(0, 0, 0, 0);
    {   // Qbf[e][d], t = e*1024+d
        float s = sig[t];
        Qbf[t] = s > THRESHF ? (unsigned short)0x3F80u
                             : (s < -THRESHF ? (unsigned short)0xBF80u : (unsigned short)0u);
    }
}

// Split-K MFMA router (proven R11): one block per 16-row group; 4 waves each
// own a 256-dim K-slice; LDS combine; wave 0 argmax + exact f64 fallback.
// Q read from the 32KB L1-resident Qbf table (R14 lesson: inline sig
// quantize put an L2-latency load on the critical chain -> 4x slower).
__global__ __launch_bounds__(256) void k_router(const float* __restrict__ x,
                                                const unsigned short* __restrict__ Qbf,
                                                unsigned* __restrict__ ctrl,
                                                int* __restrict__ idx,
                                                float* __restrict__ outIdx,
                                                unsigned short* __restrict__ Xbf,
                                                int writeXbf) {
    __shared__ float S[4][64][4];
    const int t = threadIdx.x, w = t >> 6, l = t & 63;
    const int lc = l & 15, lr = l >> 4;
    const int row0 = blockIdx.x * 16;
    const unsigned* packT = ctrl + 1024;

    const float* ax = x + (size_t)(row0 + lc) * DM + lr * 8;
    const unsigned short* qx = Qbf + (size_t)lc * DM + lr * 8;
    unsigned short* xb = Xbf + (size_t)(row0 + lc) * DM + lr * 8;

    f32x4 acc = (f32x4){0.f, 0.f, 0.f, 0.f};

    for (int kt = w * 4; kt < w * 4 + 4; ++kt) {
#pragma unroll
        for (int h = 0; h < 2; ++h) {
            const int ko = kt * 64 + h * 32;
            float4 v0 = *(const float4*)(ax + ko);
            float4 v1 = *(const float4*)(ax + ko + 4);
            bf16x8 q = *(const bf16x8*)(qx + ko);

            float f[8] = {v0.x, v0.y, v0.z, v0.w, v1.x, v1.y, v1.z, v1.w};
            bf16x8 ah, al;
#pragma unroll
            for (int j = 0; j < 8; ++j) {
                unsigned short hi = f2bf(f[j]);
                float r = f[j] - bf2f(hi);
                ah[j] = (short)hi;
                al[j] = (short)f2bf(r);
            }
            if (writeXbf) *(bf16x8*)(xb + ko) = ah;
            acc = MFMA16(ah, q, acc);
            acc = MFMA16(al, q, acc);
        }
    }

    *(f32x4*)&S[w][l][0] = acc;
    __syncthreads();
    if (w != 0) return;

#pragma unroll
    for (int s = 1; s < 4; ++s) acc += *(const f32x4*)&S[s][l][0];

    float bv[4]; int bi[4]; float gap[4];
#pragma unroll
    for (int reg = 0; reg < 4; ++reg) {
        float v = acc[reg]; int i = lc; float s = -3.4e38f;
#pragma unroll
        for (int m = 1; m < 16; m <<= 1) {
            float ov = __shfl_xor(v, m, 64);
            int oi = __shfl_xor(i, m, 64);
            float os = __shfl_xor(s, m, 64);
            bool take = (ov > v) || (ov == v && oi < i);
            float loser = take ? v : ov;
            v = take ? ov : v;
            i = take ? oi : i;
            s = fmaxf(fmaxf(s, os), loser);
        }
        bv[reg] = v; bi[reg] = i; gap[reg] = v - s;
    }

    unsigned flagsw = 0;
#pragma unroll
    for (int reg = 0; reg < 4; ++reg)
        flagsw |= (gap[reg] < MARGIN ? 1u : 0u) << reg;

    if (__any(lc == 0 && flagsw != 0)) {   // rare exact path
#pragma unroll
        for (int reg = 0; reg < 4; ++reg) {
            for (int g = 0; g < 4; ++g) {
                const unsigned fw = __shfl(flagsw, g * 16, 64);
                if ((fw >> reg) & 1u) {
                    const int row = row0 + g * 4 + reg;
                    const float* xr = x + (size_t)row * DM;
                    float xv[16]; unsigned mk[16];
#pragma unroll
                    for (int k2 = 0; k2 < 16; ++k2) {
                        xv[k2] = xr[k2 * 64 + l];
                        mk[k2] = packT[k2 * 64 + l];
                    }
                    double best = 0.0; int bbi = 0;
                    for (int e = 0; e < 16; ++e) {
                        double a = 0.0;
#pragma unroll
                        for (int k2 = 0; k2 < 16; ++k2) {
                            const int pb = (int)((mk[k2] >> e) & 1u);
                            const int mb = (int)((mk[k2] >> (16 + e)) & 1u);
                            a += pb ? (double)xv[k2] : (mb ? -(double)xv[k2] : 0.0);
                        }
#pragma unroll
                        for (int m = 1; m < 64; m <<= 1) a += __shfl_xor(a, m, 64);
                        if (e == 0 || a > best) { best = a; bbi = e; }
                    }
                    if (lr == g && lc == 0) bi[reg] = bbi;
                }
            }
        }
    }

    if (lc == 0) {
#pragma unroll
        for (int reg = 0; reg < 4; ++reg) {
            const int row = row0 + lr * 4 + reg;
            idx[row] = bi[reg];
            outIdx[row] = (float)bi[reg];
            atomicAdd(&ctrl[bi[reg] * 16], 1u);
        }
    }
}

// Fused: blocks 0..127 build perm; blocks 128.. convert W f32->bf16.
__global__ __launch_bounds__(256) void k_permconv(const int* __restrict__ idx,
                                                  unsigned* __restrict__ ctrl,
                                                  int* __restrict__ perm,
                                                  const float* __restrict__ W,
                                                  unsigned short* __restrict__ Wb) {
    if (blockIdx.x >= 128) {
        const size_t g = ((size_t)(blockIdx.x - 128) * 256 + threadIdx.x) * 8;
        float4 a = *(const float4*)&W[g];
        float4 b = *(const float4*)&W[g + 4];
        *(ushort4*)&Wb[g]     = make_ushort4(f2bf(a.x), f2bf(a.y), f2bf(a.z), f2bf(a.w));
        *(ushort4*)&Wb[g + 4] = make_ushort4(f2bf(b.x), f2bf(b.y), f2bf(b.z), f2bf(b.w));
        return;
    }
    __shared__ unsigned hcnt[16];
    __shared__ unsigned hbase[16];
    const int t = threadIdx.x;
    const int row = blockIdx.x * 256 + t;
    int tb[NE + 1];
    tile_base(ctrl, tb);
    if (t < 16) hcnt[t] = 0;
    __syncthreads();
    const int e = idx[row];
    const unsigned lrank = atomicAdd(&hcnt[e], 1u);
    __syncthreads();
    if (t < 16) hbase[t] = atomicAdd(&ctrl[256 + t * 16], hcnt[t]);
    __syncthreads();
    perm[tb[e] * 128 + hbase[e] + lrank] = row;
}

// Grouped bf16 GEMM: R7 pipeline (proven 142us; family floor per the
// R7/R8/R9/R12/R13 response surface). 128x128 tile, BK=32, 4 waves (2x2),
// A and B triple-buffered (depth-2), counted vmcnt(4), 49KB LDS -> 3 blk/CU,
// chunk-swizzle (both-sides) — conflicts 0.
__global__ __launch_bounds__(256) void k_gemm(
        const unsigned short* __restrict__ Xbf,
        const unsigned short* __restrict__ Wb,
        const float* __restrict__ bias,
        const int* __restrict__ perm,
        const unsigned* __restrict__ ctrl,
        float* __restrict__ out) {
    __shared__ unsigned short A_lds[3][128 * 32];
    __shared__ unsigned short B_lds[3][128 * 32];

    int tb[NE + 1];
    const int total = tile_base(ctrl, tb);

    // flat = 0..2175: xcd = flat&7; all 8 ny-siblings of one bx share an XCD.
    int bx, ny;
    {
        const int flat = blockIdx.x;
        const int xcd = flat & 7, s2 = flat >> 3;
        bx = xcd * 34 + (s2 >> 3);
        ny = s2 & 7;
    }
    if (bx >= total) return;
    int e = 0;
    while (e < NE - 1 && tb[e + 1] <= bx) ++e;
    const int valid = (int)ctrl[e * 16] - (bx - tb[e]) * 128;  // 1..128
    const int n0 = ny * 128;

    const int t = threadIdx.x, w = t >> 6, l = t & 63;
    const int wr = w >> 1, wc = w & 1;
    const int lc = l & 15, lr = l >> 4;
    const int hsw = ((t & 3) - ((t >> 3) & 3)) & 3;     // staged data-chunk
    const int ssw = (lr + (lc >> 1)) & 3;               // read slot-chunk

    f32x4 acc[4][4];
#pragma unroll
    for (int m = 0; m < 4; ++m)
#pragma unroll
        for (int n = 0; n < 4; ++n) acc[m][n] = (f32x4){0.f, 0.f, 0.f, 0.f};

    const size_t aRowBase = (size_t)bx * 128;
    const unsigned short* Bg = Wb + ((size_t)e * DM + n0) * DM;

    // Per-lane gathered A sources (perm prefilled 0 for pad slots).
    const int r0 = t >> 2;
    const int prow0 = perm[aRowBase + r0];
    const int prow1 = perm[aRowBase + 64 + r0];
    const unsigned short* a0 = Xbf + (size_t)prow0 * DM + hsw * 8;
    const unsigned short* a1 = Xbf + (size_t)prow1 * DM + hsw * 8;
    const unsigned short* b0 = Bg + (size_t)r0 * DM + hsw * 8;
    const unsigned short* b1 = Bg + (size_t)(64 + r0) * DM + hsw * 8;

    auto STAGE = [&](int kt, int buf) {   // 4 VMEM ops/thread
        const int ko = kt * 32;
        gload_lds16(a0 + ko, &A_lds[buf][(size_t)(w * 64) * 8]);
        gload_lds16(a1 + ko, &A_lds[buf][(size_t)(256 + w * 64) * 8]);
        gload_lds16(b0 + ko, &B_lds[buf][(size_t)(w * 64) * 8]);
        gload_lds16(b1 + ko, &B_lds[buf][(size_t)(256 + w * 64) * 8]);
    };

    STAGE(0, 0);
    STAGE(1, 1);

    const int NT = DM / 32;  // 32
    int cur = 0;
    for (int kt = 0; kt < NT; ++kt) {
        if (kt + 1 < NT) asm volatile("s_waitcnt vmcnt(4)" ::: "memory");
        else             asm volatile("s_waitcnt vmcnt(0)" ::: "memory");
        __builtin_amdgcn_sched_barrier(0);
        __builtin_amdgcn_s_barrier();
        __builtin_amdgcn_sched_barrier(0);

        if (kt + 2 < NT) {
            const int nb = (cur + 2 >= 3) ? cur - 1 : cur + 2;
            STAGE(kt + 2, nb);
        }

        bf16x8 af[4], bf[4];
#pragma unroll
        for (int m = 0; m < 4; ++m)
            af[m] = *(const bf16x8*)&A_lds[cur][(wr * 64 + m * 16 + lc) * 32 + ssw * 8];
#pragma unroll
        for (int n = 0; n < 4; ++n)
            bf[n] = *(const bf16x8*)&B_lds[cur][(wc * 64 + n * 16 + lc) * 32 + ssw * 8];
#pragma unroll
        for (int m = 0; m < 4; ++m)
#pragma unroll
            for (int n = 0; n < 4; ++n)
                acc[m][n] = MFMA16(af[m], bf[n], acc[m][n]);

        cur = (cur + 1 >= 3) ? 0 : cur + 1;
    }

    float bvv[4];
#pragma unroll
    for (int n = 0; n < 4; ++n) bvv[n] = bias[e * DM + n0 + wc * 64 + n * 16 + lc];

#pragma unroll
    for (int m = 0; m < 4; ++m) {
#pragma unroll
        for (int reg = 0; reg < 4; ++reg) {
            const int rit = wr * 64 + m * 16 + lr * 4 + reg;  // row in tile
            if (rit < valid) {
                const int orow = perm[aRowBase + rit];
                float* op = out + (size_t)orow * DM;
                const unsigned short* xr = Xbf + (size_t)orow * DM;
#pragma unroll
                for (int n = 0; n < 4; ++n) {
                    const int col = n0 + wc * 64 + n * 16 + lc;
                    float v = acc[m][n][reg] + bvv[n];
                    v = v > 0.f ? v : 0.f;
                    op[col] = v + bf2f(xr[col]);
                }
            }
        }
    }
}

// Fallback (small ws): 128x128 2-phase reg-staged f32->bf16.
__global__ __launch_bounds__(256) void k_gemm_small(
        const float* __restrict__ x, const float* __restrict__ W,
        const float* __restrict__ bias, const int* __restrict__ perm,
        const unsigned* __restrict__ ctrl, float* __restrict__ out) {
    __shared__ unsigned short A_lds[128 * 32];
    __shared__ unsigned short B_lds[128 * 32];
    int tb[NE + 1];
    const int total = tile_base(ctrl, tb);
    int bx, ny;
    {
        const int flat = blockIdx.x;
        const int xcd = flat & 7, s2 = flat >> 3;
        bx = xcd * 34 + (s2 >> 3);
        ny = s2 & 7;
    }
    if (bx >= total) return;
    int e = 0;
    while (e < NE - 1 && tb[e + 1] <= bx) ++e;
    const int valid = (int)ctrl[e * 16] - (bx - tb[e]) * 128;
    const int n0 = ny * 128;
    const int t = threadIdx.x, w = t >> 6, l = t & 63;
    const int wr = w >> 1, wc = w & 1;
    const int lc = l & 15, lr = l >> 4;
    const int hsw = ((t & 3) - ((t >> 3) & 3)) & 3;
    const int ssw = (lr + (lc >> 1)) & 3;

    f32x4 acc[4][4];
#pragma unroll
    for (int m = 0; m < 4; ++m)
#pragma unroll
        for (int n = 0; n < 4; ++n) acc[m][n] = (f32x4){0.f, 0.f, 0.f, 0.f};
    const size_t aRowBase = (size_t)bx * 128;

    for (int kt = 0; kt < DM / 32; ++kt) {
        __syncthreads();
#pragma unroll
        for (int rd = 0; rd < 2; ++rd) {
            const int c = rd * 256 + t;
            const int r = c >> 2;
            const float* wp = W + ((size_t)e * DM + n0 + r) * DM + kt * 32 + hsw * 8;
            float4 q0 = *(const float4*)wp;
            float4 q1 = *(const float4*)(wp + 4);
            *(ushort4*)&B_lds[c * 8]     = make_ushort4(f2bf(q0.x), f2bf(q0.y), f2bf(q0.z), f2bf(q0.w));
            *(ushort4*)&B_lds[c * 8 + 4] = make_ushort4(f2bf(q1.x), f2bf(q1.y), f2bf(q1.z), f2bf(q1.w));
            ushort4 p0 = make_ushort4(0, 0, 0, 0), p1 = p0;
            if (r < valid) {
                const int orow = perm[aRowBase + r];
                const float* xp = x + (size_t)orow * DM + kt * 32 + hsw * 8;
                float4 u0 = *(const float4*)xp;
                float4 u1 = *(const float4*)(xp + 4);
                p0 = make_ushort4(f2bf(u0.x), f2bf(u0.y), f2bf(u0.z), f2bf(u0.w));
                p1 = make_ushort4(f2bf(u1.x), f2bf(u1.y), f2bf(u1.z), f2bf(u1.w));
            }
            *(ushort4*)&A_lds[c * 8]     = p0;
            *(ushort4*)&A_lds[c * 8 + 4] = p1;
        }
        __syncthreads();
        bf16x8 af[4], bf[4];
#pragma unroll
        for (int m = 0; m < 4; ++m)
            af[m] = *(const bf16x8*)&A_lds[(wr * 64 + m * 16 + lc) * 32 + ssw * 8];
#pragma unroll
        for (int n = 0; n < 4; ++n)
            bf[n] = *(const bf16x8*)&B_lds[(wc * 64 + n * 16 + lc) * 32 + ssw * 8];
#pragma unroll
        for (int m = 0; m < 4; ++m)
#pragma unroll
            for (int n = 0; n < 4; ++n)
                acc[m][n] = MFMA16(af[m], bf[n], acc[m][n]);
    }

    float bvv[4];
#pragma unroll
    for (int n = 0; n < 4; ++n) bvv[n] = bias[e * DM + n0 + wc * 64 + n * 16 + lc];
#pragma unroll
    for (int m = 0; m < 4; ++m)
#pragma unroll
        for (int reg = 0; reg < 4; ++reg) {
            const int rit = wr * 64 + m * 16 + lr * 4 + reg;
            if (rit < valid) {
                const int orow = perm[aRowBase + rit];
                const float* xr = x + (size_t)orow * DM;
                float* op = out + (size_t)orow * DM;
#pragma unroll
                for (int n = 0; n < 4; ++n) {
                    const int col = n0 + wc * 64 + n * 16 + lc;
                    float v = acc[m][n][reg] + bvv[n];
                    v = v > 0.f ? v : 0.f;
                    op[col] = v + xr[col];
                }
            }
        }
}

extern "C" void kernel_launch(void* const* d_in, const int* in_sizes, int n_in,
                              void* d_out, int out_size, void* d_ws, size_t ws_size,
                              hipStream_t stream) {
    const float* x    = (const float*)d_in[0];
    const float* sig  = (const float*)d_in[1];
    const float* W    = (const float*)d_in[2];
    const float* bias = (const float*)d_in[3];
    float* out = (float*)d_out;
    float* outIdx = out + (size_t)BATCH * DM;

    char* ws = (char*)d_ws;
    int* idx = (int*)ws;
    unsigned* ctrl = (unsigned*)(ws + CTRL_OFF);
    unsigned short* Qbf = (unsigned short*)(ws + QBF_OFF);
    int* perm = (int*)(ws + PERM_OFF);
    unsigned short* Xbf = (unsigned short*)(ws + XBF_OFF);
    unsigned short* Wb = (unsigned short*)(ws + WB_OFF);

    const bool full = ws_size >= WS_NEED;

    k_init<<<64, 256, 0, stream>>>(sig, ctrl, perm, Qbf);
    k_router<<<2048, 256, 0, stream>>>(x, Qbf, ctrl, idx, outIdx, Xbf, full ? 1 : 0);
    k_permconv<<<full ? 8320 : 128, 256, 0, stream>>>(idx, ctrl, perm, W, Wb);
    if (full) {
        k_gemm<<<2176, 256, 0, stream>>>(Xbf, Wb, bias, perm, ctrl, out);
    } else {
        k_gemm_small<<<2176, 256, 0, stream>>>(x, W, bias, perm, ctrl, out);
    }
}